// Round 19
// baseline (312.416 us; speedup 1.0000x reference)
//
#include <hip/hip_runtime.h>

#define B_  128
#define LC_ 512
#define LM_ 512
#define D_  512

typedef __attribute__((ext_vector_type(8))) short short8;
typedef __attribute__((ext_vector_type(16))) float f32x16;
typedef unsigned int u32;

__device__ __forceinline__ unsigned short bf16_rn(float x) {
  unsigned u = __float_as_uint(x);
  unsigned r = u + 0x7fffu + ((u >> 16) & 1u);
  return (unsigned short)(r >> 16);
}
__device__ __forceinline__ float bf2f(short s) {
  return __uint_as_float((u32)(unsigned short)s << 16);
}
__device__ __forceinline__ void gl_lds16(const void* g, void* l) {
  __builtin_amdgcn_global_load_lds((const __attribute__((address_space(1))) u32*)g,
                                   (__attribute__((address_space(3))) u32*)l, 16, 0, 0);
}

// one fp32 -> (hi,lo) bf16 split + u-dot accumulate; constant IDX only
#define CVT1(SRC, WS, AH, AL, IDX, ACCU)                         \
  { unsigned short hb_ = bf16_rn(SRC);                           \
    float hf_ = __uint_as_float((u32)hb_ << 16);                 \
    AH[IDX] = (short)hb_;                                        \
    AL[IDX] = (short)bf16_rn((SRC) - hf_);                       \
    ACCU = fmaf((SRC), (WS), ACCU); }

// ---------------- k_cvt_main: main fp32 -> tiled fragment-order bf16 planes
__global__ __launch_bounds__(256) void k_cvt_main(
    const float* __restrict__ mn, const float* __restrict__ W,
    short* __restrict__ BtH, short* __restrict__ BtL,
    float* __restrict__ v) {
  __shared__ float sW[512];
  int tid = threadIdx.x;
  sW[tid] = W[tid];
  sW[tid + 256] = W[tid + 256];
  __syncthreads();
  int wave = blockIdx.x * 4 + (tid >> 6);
  int b = wave >> 4, mt = wave & 15;
  int lane = tid & 63, rowl = lane & 31, h = lane >> 5;
  const float* src = mn + ((size_t)b * LM_ + 32 * mt + rowl) * D_ + 8 * h;
  float acc = 0.f;
  for (int ks = 0; ks < 32; ks++) {
    float4 f0 = *(const float4*)(src + 16 * ks);
    float4 f1 = *(const float4*)(src + 16 * ks + 4);
    int k = 16 * ks + 8 * h;
    float4 w0 = *(const float4*)&sW[k];
    float4 w1 = *(const float4*)&sW[k + 4];
    short8 vh, vl;
    CVT1(f0.x, w0.x, vh, vl, 0, acc); CVT1(f0.y, w0.y, vh, vl, 1, acc);
    CVT1(f0.z, w0.z, vh, vl, 2, acc); CVT1(f0.w, w0.w, vh, vl, 3, acc);
    CVT1(f1.x, w1.x, vh, vl, 4, acc); CVT1(f1.y, w1.y, vh, vl, 5, acc);
    CVT1(f1.z, w1.z, vh, vl, 6, acc); CVT1(f1.w, w1.w, vh, vl, 7, acc);
    size_t off = (((size_t)b * 32 + ks) * 16 + mt) * 512 + (size_t)lane * 8;
    *(short8*)(BtH + off) = vh;
    *(short8*)(BtL + off) = vl;
  }
  acc += __shfl_xor(acc, 32, 64);
  if (h == 0) v[b * LM_ + 32 * mt + rowl] = acc;
}

// ---------------- K1: 128c x 512m, 16 waves (1024 thr), 4 waves/SIMD -------
// Wave wv owns m-column-tile wv (32 cols) x all 128 c-rows: acc = 4 f32x16
// (64 regs) -> fits 4 waves/SIMD. A staged via cvtA (waves 0-3, LDS), B via
// gl_lds double-buffer. Softmax/t-partials per-wave over its 32 cols.
// Numerics bit-identical to R18 (same splits, same 3-term MFMA order).
struct __align__(16) Smem10 {
  short8 Bf[2][2][16][64];   // [buf][pl][mt][lane]  64 KB
  short8 Af[2][2][4][64];    // [buf][pl][rt][lane]  16 KB
  float sW[512];             // 2 KB
  float red[16][128];        // 8 KB
  float cmb[128];
  float uld[128];
};

__global__ __launch_bounds__(1024) void k_scores_mfma10(
    const float* __restrict__ ctx, const short* __restrict__ BtH,
    const short* __restrict__ BtL, const float* __restrict__ W,
    unsigned short* __restrict__ P16, float* __restrict__ tpart) {
  __shared__ Smem10 sm;
  int p = blockIdx.x;
  int b = (p & 7) | ((p >> 5) << 3);   // 4 c-blocks of a batch -> same XCD
  int cblk = (p >> 3) & 3;
  int c0 = cblk * 128;
  int tid = threadIdx.x;
  int lane = tid & 63, wv = tid >> 6;  // wv in [0,16)
  int rowl = lane & 31, h = lane >> 5;

  f32x16 acc[4];                       // 64 acc regs: rt = 0..3
  #pragma unroll
  for (int rt = 0; rt < 4; rt++)
    #pragma unroll
    for (int j = 0; j < 16; j++) acc[rt][j] = 0.f;

  auto stageB = [&](int bf, int ks) {  // wave wv stages col-tile mt = wv
    size_t off = (((size_t)b * 32 + ks) * 16 + wv) * 512 + (size_t)lane * 8;
    gl_lds16(BtH + off, &sm.Bf[bf][0][wv][0]);
    gl_lds16(BtL + off, &sm.Bf[bf][1][wv][0]);
  };
  auto cvtA = [&](int bf, int ks, const float4& g0, const float4& g1, float& au) {
    float xs[8] = {g0.x, g0.y, g0.z, g0.w, g1.x, g1.y, g1.z, g1.w};
    int k = 16 * ks + 8 * h;
    float4 w0 = *(const float4*)&sm.sW[k];
    float4 w1 = *(const float4*)&sm.sW[k + 4];
    float ws[8] = {w0.x, w0.y, w0.z, w0.w, w1.x, w1.y, w1.z, w1.w};
    short8 vh, vl;
    #pragma unroll
    for (int e = 0; e < 8; e++) {
      unsigned short hb = bf16_rn(xs[e]);
      float hf = __uint_as_float((unsigned)hb << 16);
      vh[e] = (short)hb;
      vl[e] = (short)bf16_rn(xs[e] - hf);
      au = fmaf(xs[e], ws[e], au);
    }
    *(short8*)&sm.Af[bf][0][wv][lane] = vh;   // rt = wv (wv < 4 only)
    *(short8*)&sm.Af[bf][1][wv][lane] = vl;
  };

  if (tid < 512) sm.sW[tid] = W[tid];
  float accu = 0.f;
  stageB(0, 0);
  const float* arow = ctx + ((size_t)b * LC_ + c0 + 32 * wv + rowl) * D_ + 8 * h;
  float4 g0, g1;
  if (wv < 4) {
    g0 = *(const float4*)(arow);
    g1 = *(const float4*)(arow + 4);
  }
  __syncthreads();                      // sW visible
  if (wv < 4) cvtA(0, 0, g0, g1, accu);
  __syncthreads();                      // Af written, Bf gl_lds drained

  for (int ks = 0; ks < 32; ks++) {
    int buf = ks & 1;
    if (ks < 31) {
      stageB(buf ^ 1, ks + 1);
      if (wv < 4) {
        const float* ap = arow + 16 * (ks + 1);
        g0 = *(const float4*)ap;
        g1 = *(const float4*)(ap + 4);
      }
    }
    short8 bh = sm.Bf[buf][0][wv][lane];
    short8 bl = sm.Bf[buf][1][wv][lane];
    #pragma unroll
    for (int rt = 0; rt < 4; rt++) {
      short8 ah = sm.Af[buf][0][rt][lane];
      short8 al = sm.Af[buf][1][rt][lane];
      acc[rt] = __builtin_amdgcn_mfma_f32_32x32x16_bf16(ah, bh, acc[rt], 0, 0, 0);
      acc[rt] = __builtin_amdgcn_mfma_f32_32x32x16_bf16(ah, bl, acc[rt], 0, 0, 0);
      acc[rt] = __builtin_amdgcn_mfma_f32_32x32x16_bf16(al, bh, acc[rt], 0, 0, 0);
    }
    if (ks < 31 && wv < 4) cvtA(buf ^ 1, ks + 1, g0, g1, accu);
    __syncthreads();
  }

  // u for the block's 128 c-rows (waves 0-3 computed rows 32wv+rowl)
  if (wv < 4) {
    accu += __shfl_xor(accu, 32, 64);
    if (h == 0) sm.uld[32 * wv + rowl] = accu;
  }

  // ---- softmax over m=512 per c-row: wave-local max over its 32 cols ----
  #pragma unroll
  for (int rt = 0; rt < 4; rt++)
    #pragma unroll
    for (int j = 0; j < 16; j++) {
      float mx = acc[rt][j];
      #pragma unroll
      for (int s = 1; s <= 16; s <<= 1) mx = fmaxf(mx, __shfl_xor(mx, s, 64));
      if (rowl == 0)
        sm.red[wv][32 * rt + (j & 3) + 8 * (j >> 2) + 4 * h] = mx;
    }
  __syncthreads();
  if (tid < 128) {
    float m0 = sm.red[0][tid];
    #pragma unroll
    for (int w2 = 1; w2 < 16; w2++) m0 = fmaxf(m0, sm.red[w2][tid]);
    sm.cmb[tid] = m0;
  }
  __syncthreads();
  #pragma unroll
  for (int rt = 0; rt < 4; rt++)
    #pragma unroll
    for (int j = 0; j < 16; j++) {
      int row = 32 * rt + (j & 3) + 8 * (j >> 2) + 4 * h;
      float e = __expf(acc[rt][j] - sm.cmb[row]);
      acc[rt][j] = e;
      float s = e;
      #pragma unroll
      for (int st = 1; st <= 16; st <<= 1) s += __shfl_xor(s, st, 64);
      if (rowl == 0) sm.red[wv][row] = s;
    }
  __syncthreads();
  if (tid < 128) {
    float s0 = sm.red[0][tid];
    #pragma unroll
    for (int w2 = 1; w2 < 16; w2++) s0 += sm.red[w2][tid];
    sm.cmb[tid] = s0;
  }
  __syncthreads();

  // ---- P write (bf16) + fused t-partials (fp32); wave owns col 32wv+rowl --
  unsigned short* Pb = P16 + ((size_t)b * LC_ + c0) * LM_;
  float tp = 0.f;
  int col = 32 * wv + rowl;
  #pragma unroll
  for (int rt = 0; rt < 4; rt++)
    #pragma unroll
    for (int j = 0; j < 16; j++) {
      int row = 32 * rt + (j & 3) + 8 * (j >> 2) + 4 * h;
      float pv = acc[rt][j] * (1.f / sm.cmb[row]);
      Pb[(size_t)row * LM_ + col] = bf16_rn(pv);
      tp = fmaf(pv, sm.uld[row], tp);
    }
  tp += __shfl_xor(tp, 32, 64);        // sum the two h-halves (same col)
  if (h == 0)
    tpart[((size_t)b * 4 + cblk) * LM_ + col] = tp;
}

// ---------------- k_tw: t = v - sum(tpart, 4); w = softmax(t) --------------
__global__ __launch_bounds__(256) void k_tw(const float* __restrict__ tpart,
                                            const float* __restrict__ v,
                                            float* __restrict__ w_) {
  int b = blockIdx.x;
  int tid = threadIdx.x;
  int m0 = tid * 2;
  const float* tp = tpart + (size_t)b * 4 * LM_;
  float s0 = 0.f, s1 = 0.f;
  #pragma unroll
  for (int cb = 0; cb < 4; cb++) {
    s0 += tp[cb * LM_ + m0];
    s1 += tp[cb * LM_ + m0 + 1];
  }
  float x0 = v[b * LM_ + m0] - s0;
  float x1 = v[b * LM_ + m0 + 1] - s1;
  float mx = fmaxf(x0, x1);
  #pragma unroll
  for (int s = 32; s >= 1; s >>= 1) mx = fmaxf(mx, __shfl_xor(mx, s, 64));
  __shared__ float redm[4], reds[4];
  int wvv = tid >> 6, ln = tid & 63;
  if (ln == 0) redm[wvv] = mx;
  __syncthreads();
  mx = fmaxf(fmaxf(redm[0], redm[1]), fmaxf(redm[2], redm[3]));
  float e0 = __expf(x0 - mx), e1 = __expf(x1 - mx);
  float sum = e0 + e1;
  #pragma unroll
  for (int s = 32; s >= 1; s >>= 1) sum += __shfl_xor(sum, s, 64);
  if (ln == 0) reds[wvv] = sum;
  __syncthreads();
  sum = reds[0] + reds[1] + reds[2] + reds[3];
  float rinv = 1.0f / sum;
  float2 o; o.x = e0 * rinv; o.y = e1 * rinv;
  *(float2*)&w_[b * LM_ + m0] = o;
}

// ---------------- k_q: q[b,c] = sum_m bf16(P)[b,c,m]*w[b,m] ----------------
__global__ __launch_bounds__(256) void k_q(const unsigned short* __restrict__ P16,
                                           const float* __restrict__ w,
                                           float* __restrict__ q) {
  int b = blockIdx.y;
  int c0 = blockIdx.x * 32;
  int wvv = threadIdx.x >> 6, ln = threadIdx.x & 63;
  __shared__ float sw[LM_];
  *(float2*)&sw[threadIdx.x * 2] = *(const float2*)&w[b * LM_ + threadIdx.x * 2];
  __syncthreads();
  #pragma unroll
  for (int rr = 0; rr < 8; rr++) {
    int c = c0 + wvv * 8 + rr;
    short8 pv = *((const short8*)(P16 + ((size_t)b * LC_ + c) * LM_) + ln);
    float4 w0 = *(const float4*)&sw[ln * 8];
    float4 w1 = *(const float4*)&sw[ln * 8 + 4];
    float acc = bf2f(pv[0]) * w0.x + bf2f(pv[1]) * w0.y
              + bf2f(pv[2]) * w0.z + bf2f(pv[3]) * w0.w
              + bf2f(pv[4]) * w1.x + bf2f(pv[5]) * w1.y
              + bf2f(pv[6]) * w1.z + bf2f(pv[7]) * w1.w;
    #pragma unroll
    for (int s = 32; s >= 1; s >>= 1) acc += __shfl_xor(acc, s, 64);
    if (ln == 0) q[b * LC_ + c] = acc;
  }
}

// ---------------- k_out: out[b,d] = sum_m w*main(planes) - sum_c q*ctx -----
__global__ __launch_bounds__(256) void k_out(const float* __restrict__ ctx,
                                             const short* __restrict__ BtH,
                                             const short* __restrict__ BtL,
                                             const float* __restrict__ w,
                                             const float* __restrict__ q,
                                             float* __restrict__ out) {
  int b = blockIdx.y;
  int d0 = blockIdx.x * 64;
  int ks0 = d0 >> 4;                 // 4 ks-slices cover this 64-wide d block
  int tid = threadIdx.x;
  int lane = tid & 63, wvv = tid >> 6;
  int rowl = lane & 31, h = lane >> 5;
  __shared__ float sw_[LM_];
  __shared__ float redo[4][64];
  __shared__ float red2[4][64];
  sw_[tid] = w[b * LM_ + tid];
  sw_[tid + 256] = w[b * LM_ + tid + 256];
  __syncthreads();

  // ---- main part from planes: wave wvv handles mt = wvv, wvv+4, ... ----
  float mp[4][8];
  #pragma unroll
  for (int ksl = 0; ksl < 4; ksl++)
    #pragma unroll
    for (int e = 0; e < 8; e++) mp[ksl][e] = 0.f;
  for (int mt = wvv; mt < 16; mt += 4) {
    float wm = sw_[32 * mt + rowl];
    #pragma unroll
    for (int ksl = 0; ksl < 4; ksl++) {
      size_t off = (((size_t)b * 32 + ks0 + ksl) * 16 + mt) * 512 + (size_t)lane * 8;
      short8 hh = *(const short8*)(BtH + off);
      short8 ll = *(const short8*)(BtL + off);
      #pragma unroll
      for (int e = 0; e < 8; e++)
        mp[ksl][e] = fmaf(wm, bf2f(hh[e]) + bf2f(ll[e]), mp[ksl][e]);
    }
  }
  #pragma unroll
  for (int ksl = 0; ksl < 4; ksl++)
    #pragma unroll
    for (int e = 0; e < 8; e++) {
      float vsum = mp[ksl][e];
      #pragma unroll
      for (int s = 1; s <= 16; s <<= 1) vsum += __shfl_xor(vsum, s, 64);
      mp[ksl][e] = vsum;
    }
  if (rowl == 0) {
    #pragma unroll
    for (int ksl = 0; ksl < 4; ksl++)
      #pragma unroll
      for (int e = 0; e < 8; e++)
        redo[wvv][16 * ksl + 8 * h + e] = mp[ksl][e];
  }

  // ---- ctx part (fp32) ----
  int td = tid & 63;
  int tg = tid >> 6;
  const float* Cb = ctx + (size_t)b * LC_ * D_ + d0;
  const float* qb = q + b * LC_;
  float acc = 0.f;
  #pragma unroll 4
  for (int c = tg; c < LC_; c += 4) acc -= qb[c] * Cb[(size_t)c * D_ + td];
  red2[tg][td] = acc;
  __syncthreads();
  if (tg == 0)
    out[b * D_ + d0 + td] =
        redo[0][td] + redo[1][td] + redo[2][td] + redo[3][td] +
        red2[0][td] + red2[1][td] + red2[2][td] + red2[3][td];
}

// =====================  LAUNCH  ============================================
extern "C" void kernel_launch(void* const* d_in, const int* in_sizes, int n_in,
                              void* d_out, int out_size, void* d_ws, size_t ws_size,
                              hipStream_t stream) {
  const float* ctx = (const float*)d_in[0];
  const float* mn  = (const float*)d_in[1];
  const float* W   = (const float*)d_in[2];
  float* out = (float*)d_out;

  char* base = (char*)d_ws;
  size_t nP16   = (size_t)B_ * LC_ * LM_ * 2;        // 67 MB (bf16 P)
  size_t planeB = (size_t)B_ * LM_ * D_ * 2;         // 67 MB per plane

  unsigned short* P16 = (unsigned short*)base;
  short* BtH = (short*)(base + nP16);
  short* BtL = (short*)(base + nP16 + planeB);
  char* p2 = base + nP16 + 2 * planeB;
  float* tpart = (float*)p2;  p2 += (size_t)B_ * 4 * LM_ * 4;
  float* v = (float*)p2;      p2 += (size_t)B_ * LM_ * 4;
  float* w = (float*)p2;      p2 += (size_t)B_ * LM_ * 4;
  float* q = (float*)p2;

  k_cvt_main<<<dim3(512), 256, 0, stream>>>(mn, W, BtH, BtL, v);
  k_scores_mfma10<<<dim3(512), 1024, 0, stream>>>(ctx, BtH, BtL, W, P16, tpart);
  k_tw<<<dim3(B_), 256, 0, stream>>>(tpart, v, w);
  k_q<<<dim3(LC_ / 32, B_), 256, 0, stream>>>(P16, w, q);
  k_out<<<dim3(D_ / 64, B_), 256, 0, stream>>>(ctx, BtH, BtL, w, q, out);
}

// Round 20
// 255.332 us; speedup vs baseline: 1.2236x; 1.2236x over previous
//
#include <hip/hip_runtime.h>

#define B_  128
#define LC_ 512
#define LM_ 512
#define D_  512

typedef __attribute__((ext_vector_type(8))) short short8;
typedef __attribute__((ext_vector_type(16))) float f32x16;
typedef unsigned int u32;

__device__ __forceinline__ unsigned short bf16_rn(float x) {
  unsigned u = __float_as_uint(x);
  unsigned r = u + 0x7fffu + ((u >> 16) & 1u);
  return (unsigned short)(r >> 16);
}
__device__ __forceinline__ float bf2f(short s) {
  return __uint_as_float((u32)(unsigned short)s << 16);
}
__device__ __forceinline__ void gl_lds16(const void* g, void* l) {
  __builtin_amdgcn_global_load_lds((const __attribute__((address_space(1))) u32*)g,
                                   (__attribute__((address_space(3))) u32*)l, 16, 0, 0);
}

// one fp32 -> (hi,lo) bf16 split + u-dot accumulate; constant IDX only
#define CVT1(SRC, WS, AH, AL, IDX, ACCU)                         \
  { unsigned short hb_ = bf16_rn(SRC);                           \
    float hf_ = __uint_as_float((u32)hb_ << 16);                 \
    AH[IDX] = (short)hb_;                                        \
    AL[IDX] = (short)bf16_rn((SRC) - hf_);                       \
    ACCU = fmaf((SRC), (WS), ACCU); }

// ---------------- k_cvt_main: main fp32 -> tiled fragment-order bf16 planes
// Bt[b][ks][mt][lane][8]; also fused v = main·W. Wave = one (b, mt) tile.
__global__ __launch_bounds__(256) void k_cvt_main(
    const float* __restrict__ mn, const float* __restrict__ W,
    short* __restrict__ BtH, short* __restrict__ BtL,
    float* __restrict__ v) {
  __shared__ float sW[512];
  int tid = threadIdx.x;
  sW[tid] = W[tid];
  sW[tid + 256] = W[tid + 256];
  __syncthreads();
  int wave = blockIdx.x * 4 + (tid >> 6);
  int b = wave >> 4, mt = wave & 15;
  int lane = tid & 63, rowl = lane & 31, h = lane >> 5;
  const float* src = mn + ((size_t)b * LM_ + 32 * mt + rowl) * D_ + 8 * h;
  float acc = 0.f;
  for (int ks = 0; ks < 32; ks++) {
    float4 f0 = *(const float4*)(src + 16 * ks);
    float4 f1 = *(const float4*)(src + 16 * ks + 4);
    int k = 16 * ks + 8 * h;
    float4 w0 = *(const float4*)&sW[k];
    float4 w1 = *(const float4*)&sW[k + 4];
    short8 vh, vl;
    CVT1(f0.x, w0.x, vh, vl, 0, acc); CVT1(f0.y, w0.y, vh, vl, 1, acc);
    CVT1(f0.z, w0.z, vh, vl, 2, acc); CVT1(f0.w, w0.w, vh, vl, 3, acc);
    CVT1(f1.x, w1.x, vh, vl, 4, acc); CVT1(f1.y, w1.y, vh, vl, 5, acc);
    CVT1(f1.z, w1.z, vh, vl, 6, acc); CVT1(f1.w, w1.w, vh, vl, 7, acc);
    size_t off = (((size_t)b * 32 + ks) * 16 + mt) * 512 + (size_t)lane * 8;
    *(short8*)(BtH + off) = vh;
    *(short8*)(BtL + off) = vl;
  }
  acc += __shfl_xor(acc, 32, 64);
  if (h == 0) v[b * LM_ + 32 * mt + rowl] = acc;
}

// ---------------- K1: R7 structure (proven), P stored as bf16 --------------
struct __align__(16) Smem3 {
  short8 Bf[2][2][16][64];   // [buf][pl][mt][lane]  64 KB
  short8 Af[2][2][4][64];    // [buf][pl][rt][lane]  16 KB
  float sW[512];
  float red[4][128];
  float cmb[128];
  float uld[128];
  float tpw[2][4][128];
};

__global__ __launch_bounds__(512, 2) void k_scores_mfma9(
    const float* __restrict__ ctx, const short* __restrict__ BtH,
    const short* __restrict__ BtL, const float* __restrict__ W,
    unsigned short* __restrict__ P16, float* __restrict__ tpart) {
  __shared__ Smem3 sm;
  int p = blockIdx.x;
  int b = (p & 7) | ((p >> 5) << 3);   // 4 c-blocks of a batch -> same XCD
  int cblk = (p >> 3) & 3;
  int c0 = cblk * 128;
  int tid = threadIdx.x;
  int lane = tid & 63, wv = tid >> 6;
  int rowl = lane & 31, h = lane >> 5;

  f32x16 acc[2][4];
  #pragma unroll
  for (int r = 0; r < 2; r++)
    #pragma unroll
    for (int mtl = 0; mtl < 4; mtl++)
      #pragma unroll
      for (int j = 0; j < 16; j++) acc[r][mtl][j] = 0.f;

  auto stageB = [&](int bf, int ks) {
    #pragma unroll
    for (int rep = 0; rep < 2; rep++) {
      int mt = wv + 8 * rep;
      size_t off = (((size_t)b * 32 + ks) * 16 + mt) * 512 + (size_t)lane * 8;
      gl_lds16(BtH + off, &sm.Bf[bf][0][mt][0]);
      gl_lds16(BtL + off, &sm.Bf[bf][1][mt][0]);
    }
  };
  auto cvtA = [&](int bf, int ks, const float4& g0, const float4& g1, float& au) {
    float xs[8] = {g0.x, g0.y, g0.z, g0.w, g1.x, g1.y, g1.z, g1.w};
    int k = 16 * ks + 8 * h;
    float4 w0 = *(const float4*)&sm.sW[k];
    float4 w1 = *(const float4*)&sm.sW[k + 4];
    float ws[8] = {w0.x, w0.y, w0.z, w0.w, w1.x, w1.y, w1.z, w1.w};
    short8 vh, vl;
    #pragma unroll
    for (int e = 0; e < 8; e++) {
      unsigned short hb = bf16_rn(xs[e]);
      float hf = __uint_as_float((unsigned)hb << 16);
      vh[e] = (short)hb;
      vl[e] = (short)bf16_rn(xs[e] - hf);
      au = fmaf(xs[e], ws[e], au);
    }
    *(short8*)&sm.Af[bf][0][wv][lane] = vh;
    *(short8*)&sm.Af[bf][1][wv][lane] = vl;
  };

  sm.sW[tid] = W[tid];
  float accu = 0.f;
  stageB(0, 0);
  const float* arow = ctx + ((size_t)b * LC_ + c0 + 32 * wv + rowl) * D_ + 8 * h;
  float4 g0, g1;
  if (wv < 4) {
    g0 = *(const float4*)(arow);
    g1 = *(const float4*)(arow + 4);
  }
  __syncthreads();                      // sW visible
  if (wv < 4) cvtA(0, 0, g0, g1, accu);
  __syncthreads();                      // Af written, Bf gl_lds drained

  for (int ks = 0; ks < 32; ks++) {
    int buf = ks & 1;
    if (ks < 31) {
      stageB(buf ^ 1, ks + 1);
      if (wv < 4) {
        const float* ap = arow + 16 * (ks + 1);
        g0 = *(const float4*)ap;
        g1 = *(const float4*)(ap + 4);
      }
    }
    int rt0 = (wv >> 2) * 2;
    short8 ah0 = sm.Af[buf][0][rt0][lane];
    short8 ah1 = sm.Af[buf][0][rt0 + 1][lane];
    short8 al0 = sm.Af[buf][1][rt0][lane];
    short8 al1 = sm.Af[buf][1][rt0 + 1][lane];
    #pragma unroll
    for (int mtl = 0; mtl < 4; mtl++) {
      int mtg = (wv & 3) * 4 + mtl;
      short8 bh = sm.Bf[buf][0][mtg][lane];
      short8 bl = sm.Bf[buf][1][mtg][lane];
      acc[0][mtl] = __builtin_amdgcn_mfma_f32_32x32x16_bf16(ah0, bh, acc[0][mtl], 0, 0, 0);
      acc[0][mtl] = __builtin_amdgcn_mfma_f32_32x32x16_bf16(ah0, bl, acc[0][mtl], 0, 0, 0);
      acc[0][mtl] = __builtin_amdgcn_mfma_f32_32x32x16_bf16(al0, bh, acc[0][mtl], 0, 0, 0);
      acc[1][mtl] = __builtin_amdgcn_mfma_f32_32x32x16_bf16(ah1, bh, acc[1][mtl], 0, 0, 0);
      acc[1][mtl] = __builtin_amdgcn_mfma_f32_32x32x16_bf16(ah1, bl, acc[1][mtl], 0, 0, 0);
      acc[1][mtl] = __builtin_amdgcn_mfma_f32_32x32x16_bf16(al1, bh, acc[1][mtl], 0, 0, 0);
    }
    if (ks < 31 && wv < 4) cvtA(buf ^ 1, ks + 1, g0, g1, accu);
    __syncthreads();
  }

  // u for this block's 128 c-rows (stage waves computed the dot)
  if (wv < 4) {
    accu += __shfl_xor(accu, 32, 64);
    if (h == 0) sm.uld[32 * wv + rowl] = accu;
  }

  // ---- softmax over m=512 per c-row (cross-wave via LDS) ----
  #pragma unroll
  for (int r = 0; r < 2; r++)
    #pragma unroll
    for (int j = 0; j < 16; j++) {
      float mx = fmaxf(fmaxf(acc[r][0][j], acc[r][1][j]),
                       fmaxf(acc[r][2][j], acc[r][3][j]));
      #pragma unroll
      for (int s = 1; s <= 16; s <<= 1) mx = fmaxf(mx, __shfl_xor(mx, s, 64));
      if (rowl == 0)
        sm.red[wv & 3][64 * (wv >> 2) + 32 * r + (j & 3) + 8 * (j >> 2) + 4 * h] = mx;
    }
  __syncthreads();
  if (tid < 128)
    sm.cmb[tid] = fmaxf(fmaxf(sm.red[0][tid], sm.red[1][tid]),
                        fmaxf(sm.red[2][tid], sm.red[3][tid]));
  __syncthreads();
  #pragma unroll
  for (int r = 0; r < 2; r++)
    #pragma unroll
    for (int j = 0; j < 16; j++) {
      int row = 64 * (wv >> 2) + 32 * r + (j & 3) + 8 * (j >> 2) + 4 * h;
      float mx = sm.cmb[row];
      float s = 0.f;
      #pragma unroll
      for (int mtl = 0; mtl < 4; mtl++) {
        float e = __expf(acc[r][mtl][j] - mx);
        acc[r][mtl][j] = e;
        s += e;
      }
      #pragma unroll
      for (int st = 1; st <= 16; st <<= 1) s += __shfl_xor(s, st, 64);
      if (rowl == 0) sm.red[wv & 3][row] = s;
    }
  __syncthreads();
  if (tid < 128)
    sm.cmb[tid] = sm.red[0][tid] + sm.red[1][tid] + sm.red[2][tid] + sm.red[3][tid];
  __syncthreads();

  // ---- P write (bf16) + fused t-partials (fp32) ----
  unsigned short* Pb = P16 + ((size_t)b * LC_ + c0) * LM_;
  float tp[4] = {0.f, 0.f, 0.f, 0.f};
  #pragma unroll
  for (int r = 0; r < 2; r++)
    #pragma unroll
    for (int j = 0; j < 16; j++) {
      int row = 64 * (wv >> 2) + 32 * r + (j & 3) + 8 * (j >> 2) + 4 * h;
      float rinv = 1.f / sm.cmb[row];
      float uu = sm.uld[row];
      #pragma unroll
      for (int mtl = 0; mtl < 4; mtl++) {
        float pv = acc[r][mtl][j] * rinv;
        Pb[(size_t)row * LM_ + 128 * (wv & 3) + 32 * mtl + rowl] = bf16_rn(pv);
        tp[mtl] = fmaf(pv, uu, tp[mtl]);
      }
    }
  #pragma unroll
  for (int mtl = 0; mtl < 4; mtl++) tp[mtl] += __shfl_xor(tp[mtl], 32, 64);
  if (h == 0) {
    #pragma unroll
    for (int mtl = 0; mtl < 4; mtl++)
      sm.tpw[wv >> 2][wv & 3][32 * mtl + rowl] = tp[mtl];
  }
  __syncthreads();
  {
    int m = tid;
    tpart[((size_t)b * 4 + cblk) * LM_ + m] =
        sm.tpw[0][m >> 7][m & 127] + sm.tpw[1][m >> 7][m & 127];
  }
}

// ---------------- k_tw: t = v - sum(tpart, 4); w = softmax(t) --------------
__global__ __launch_bounds__(256) void k_tw(const float* __restrict__ tpart,
                                            const float* __restrict__ v,
                                            float* __restrict__ w_) {
  int b = blockIdx.x;
  int tid = threadIdx.x;
  int m0 = tid * 2;
  const float* tp = tpart + (size_t)b * 4 * LM_;
  float s0 = 0.f, s1 = 0.f;
  #pragma unroll
  for (int cb = 0; cb < 4; cb++) {
    s0 += tp[cb * LM_ + m0];
    s1 += tp[cb * LM_ + m0 + 1];
  }
  float x0 = v[b * LM_ + m0] - s0;
  float x1 = v[b * LM_ + m0 + 1] - s1;
  float mx = fmaxf(x0, x1);
  #pragma unroll
  for (int s = 32; s >= 1; s >>= 1) mx = fmaxf(mx, __shfl_xor(mx, s, 64));
  __shared__ float redm[4], reds[4];
  int wvv = tid >> 6, ln = tid & 63;
  if (ln == 0) redm[wvv] = mx;
  __syncthreads();
  mx = fmaxf(fmaxf(redm[0], redm[1]), fmaxf(redm[2], redm[3]));
  float e0 = __expf(x0 - mx), e1 = __expf(x1 - mx);
  float sum = e0 + e1;
  #pragma unroll
  for (int s = 32; s >= 1; s >>= 1) sum += __shfl_xor(sum, s, 64);
  if (ln == 0) reds[wvv] = sum;
  __syncthreads();
  sum = reds[0] + reds[1] + reds[2] + reds[3];
  float rinv = 1.0f / sum;
  float2 o; o.x = e0 * rinv; o.y = e1 * rinv;
  *(float2*)&w_[b * LM_ + m0] = o;
}

// ---------------- k_q: q[b,c] = sum_m bf16(P)[b,c,m]*w[b,m] ----------------
__global__ __launch_bounds__(256) void k_q(const unsigned short* __restrict__ P16,
                                           const float* __restrict__ w,
                                           float* __restrict__ q) {
  int b = blockIdx.y;
  int c0 = blockIdx.x * 32;
  int wvv = threadIdx.x >> 6, ln = threadIdx.x & 63;
  __shared__ float sw[LM_];
  *(float2*)&sw[threadIdx.x * 2] = *(const float2*)&w[b * LM_ + threadIdx.x * 2];
  __syncthreads();
  #pragma unroll
  for (int rr = 0; rr < 8; rr++) {
    int c = c0 + wvv * 8 + rr;
    short8 pv = *((const short8*)(P16 + ((size_t)b * LC_ + c) * LM_) + ln);
    float4 w0 = *(const float4*)&sw[ln * 8];
    float4 w1 = *(const float4*)&sw[ln * 8 + 4];
    float acc = bf2f(pv[0]) * w0.x + bf2f(pv[1]) * w0.y
              + bf2f(pv[2]) * w0.z + bf2f(pv[3]) * w0.w
              + bf2f(pv[4]) * w1.x + bf2f(pv[5]) * w1.y
              + bf2f(pv[6]) * w1.z + bf2f(pv[7]) * w1.w;
    #pragma unroll
    for (int s = 32; s >= 1; s >>= 1) acc += __shfl_xor(acc, s, 64);
    if (ln == 0) q[b * LC_ + c] = acc;
  }
}

// ---------------- k_out: out[b,d] = sum_m w*main(planes) - sum_c q*ctx -----
// main-part reads the bf16 hi/lo planes (exact to 2^-17), ctx-part fp32.
__global__ __launch_bounds__(256) void k_out(const float* __restrict__ ctx,
                                             const short* __restrict__ BtH,
                                             const short* __restrict__ BtL,
                                             const float* __restrict__ w,
                                             const float* __restrict__ q,
                                             float* __restrict__ out) {
  int b = blockIdx.y;
  int d0 = blockIdx.x * 64;
  int ks0 = d0 >> 4;                 // 4 ks-slices cover this 64-wide d block
  int tid = threadIdx.x;
  int lane = tid & 63, wvv = tid >> 6;
  int rowl = lane & 31, h = lane >> 5;
  __shared__ float sw_[LM_];
  __shared__ float redo[4][64];
  __shared__ float red2[4][64];
  sw_[tid] = w[b * LM_ + tid];
  sw_[tid + 256] = w[b * LM_ + tid + 256];
  __syncthreads();

  // ---- main part from planes: wave wvv handles mt = wvv, wvv+4, ... ----
  float mp[4][8];
  #pragma unroll
  for (int ksl = 0; ksl < 4; ksl++)
    #pragma unroll
    for (int e = 0; e < 8; e++) mp[ksl][e] = 0.f;
  for (int mt = wvv; mt < 16; mt += 4) {
    float wm = sw_[32 * mt + rowl];
    #pragma unroll
    for (int ksl = 0; ksl < 4; ksl++) {
      size_t off = (((size_t)b * 32 + ks0 + ksl) * 16 + mt) * 512 + (size_t)lane * 8;
      short8 hh = *(const short8*)(BtH + off);
      short8 ll = *(const short8*)(BtL + off);
      #pragma unroll
      for (int e = 0; e < 8; e++)
        mp[ksl][e] = fmaf(wm, bf2f(hh[e]) + bf2f(ll[e]), mp[ksl][e]);
    }
  }
  // reduce over the 32 rowl lanes (xor steps stay within each h-half)
  #pragma unroll
  for (int ksl = 0; ksl < 4; ksl++)
    #pragma unroll
    for (int e = 0; e < 8; e++) {
      float vsum = mp[ksl][e];
      #pragma unroll
      for (int s = 1; s <= 16; s <<= 1) vsum += __shfl_xor(vsum, s, 64);
      mp[ksl][e] = vsum;
    }
  if (rowl == 0) {
    #pragma unroll
    for (int ksl = 0; ksl < 4; ksl++)
      #pragma unroll
      for (int e = 0; e < 8; e++)
        redo[wvv][16 * ksl + 8 * h + e] = mp[ksl][e];
  }

  // ---- ctx part (fp32) ----
  int td = tid & 63;
  int tg = tid >> 6;
  const float* Cb = ctx + (size_t)b * LC_ * D_ + d0;
  const float* qb = q + b * LC_;
  float acc = 0.f;
  #pragma unroll 4
  for (int c = tg; c < LC_; c += 4) acc -= qb[c] * Cb[(size_t)c * D_ + td];
  red2[tg][td] = acc;
  __syncthreads();
  if (tg == 0)
    out[b * D_ + d0 + td] =
        redo[0][td] + redo[1][td] + redo[2][td] + redo[3][td] +
        red2[0][td] + red2[1][td] + red2[2][td] + red2[3][td];
}

// =====================  LAUNCH  ============================================
extern "C" void kernel_launch(void* const* d_in, const int* in_sizes, int n_in,
                              void* d_out, int out_size, void* d_ws, size_t ws_size,
                              hipStream_t stream) {
  const float* ctx = (const float*)d_in[0];
  const float* mn  = (const float*)d_in[1];
  const float* W   = (const float*)d_in[2];
  float* out = (float*)d_out;

  char* base = (char*)d_ws;
  size_t nP16   = (size_t)B_ * LC_ * LM_ * 2;        // 67 MB (bf16 P)
  size_t planeB = (size_t)B_ * LM_ * D_ * 2;         // 67 MB per plane

  unsigned short* P16 = (unsigned short*)base;
  short* BtH = (short*)(base + nP16);
  short* BtL = (short*)(base + nP16 + planeB);
  char* p2 = base + nP16 + 2 * planeB;
  float* tpart = (float*)p2;  p2 += (size_t)B_ * 4 * LM_ * 4;
  float* v = (float*)p2;      p2 += (size_t)B_ * LM_ * 4;
  float* w = (float*)p2;      p2 += (size_t)B_ * LM_ * 4;
  float* q = (float*)p2;

  k_cvt_main<<<dim3(512), 256, 0, stream>>>(mn, W, BtH, BtL, v);
  k_scores_mfma9<<<dim3(512), 512, 0, stream>>>(ctx, BtH, BtL, W, P16, tpart);
  k_tw<<<dim3(B_), 256, 0, stream>>>(tpart, v, w);
  k_q<<<dim3(LC_ / 32, B_), 256, 0, stream>>>(P16, w, q);
  k_out<<<dim3(D_ / 64, B_), 256, 0, stream>>>(ctx, BtH, BtL, w, q, out);
}